// Round 1
// baseline (18.459 us; speedup 1.0000x reference)
//
#include <hip/hip_runtime.h>
#include <math.h>

#define NP3 19200
#define NP4 4800
#define NP5 1200
#define NA  (NP3 + NP4 + NP5)   // 25200
#define MGT 64

// SCALE_CLAMP = log(224/8) = log(28)
#define SCALE_CLAMP_F 3.3322045101752038f
#define NEG_BIG (-100000000.0f)

// half_w, half_h per (level, aspect_ratio); computed in double (math.sqrt) then
// rounded to f32, matching the reference's host-side anchor constants.
// area = (stride*4)^2 ; w = sqrt(area/ar), h = area/w ; halves = w/2, h/2
__constant__ float c_half[3][3][2] = {
    // p3: area = 1024
    {{22.62741699796952f, 11.313708498984761f},   // ar = 0.5
     {16.0f, 16.0f},                              // ar = 1.0
     {11.313708498984761f, 22.62741699796952f}},  // ar = 2.0
    // p4: area = 4096
    {{45.25483399593904f, 22.62741699796952f},
     {32.0f, 32.0f},
     {22.62741699796952f, 45.25483399593904f}},
    // p5: area = 16384
    {{90.50966799187808f, 45.25483399593904f},
     {64.0f, 64.0f},
     {45.25483399593904f, 90.50966799187808f}},
};

__global__ __launch_bounds__(256)
void rpn_fused_kernel(const float* __restrict__ loc3,
                      const float* __restrict__ loc4,
                      const float* __restrict__ loc5,
                      const float* __restrict__ del3,
                      const float* __restrict__ del4,
                      const float* __restrict__ del5,
                      const float* __restrict__ gt,     // 64 x 5
                      float* __restrict__ out)
{
    __shared__ float sgt[MGT * 5];
    const int t = threadIdx.x;
    for (int i = t; i < MGT * 5; i += 256) sgt[i] = gt[i];
    __syncthreads();

    const int a = blockIdx.x * 256 + t;
    if (a >= NA) return;

    // ---- level decode ----
    int lvl, rel;
    const float* locs;
    const float* dels;
    if (a < NP3)              { lvl = 0; rel = a;              locs = loc3; dels = del3; }
    else if (a < NP3 + NP4)   { lvl = 1; rel = a - NP3;        locs = loc4; dels = del4; }
    else                      { lvl = 2; rel = a - NP3 - NP4;  locs = loc5; dels = del5; }

    const int li = rel / 3;
    const int ar = rel - li * 3;

    // ---- anchor ----
    const float lx = locs[li * 2 + 0];
    const float ly = locs[li * 2 + 1];
    const float hw = c_half[lvl][ar][0];
    const float hh = c_half[lvl][ar][1];
    const float x0 = lx - hw, y0 = ly - hh;
    const float x1 = lx + hw, y1 = ly + hh;

    const float px = (x0 + x1) * 0.5f;
    const float py = (y0 + y1) * 0.5f;
    const float pw = fabsf(x0 - x1);
    const float ph = fabsf(y0 - y1);

    // ---- apply_deltas (proposals) ----
    {
        const float tx = dels[rel * 4 + 0];
        const float ty = dels[rel * 4 + 1];
        const float tw = fminf(dels[rel * 4 + 2], SCALE_CLAMP_F);
        const float th = fminf(dels[rel * 4 + 3], SCALE_CLAMP_F);
        const float bx = px + pw * tx;
        const float by = py + ph * ty;
        const float bw = pw * __expf(tw) == 0.f ? 0.f : pw * expf(tw); // keep precise expf
        const float bh = ph * expf(th);
        float4 prop;
        prop.x = bx - bw * 0.5f;
        prop.y = by - bh * 0.5f;
        prop.z = bx + bw * 0.5f;
        prop.w = by + bw * 0.5f;   // NOTE: reference uses bw here (reference bug, replicated)
        *reinterpret_cast<float4*>(out + (size_t)a * 4) = prop;
    }

    // ---- IoU match against 64 GT boxes ----
    const float area1 = fabsf((x0 - x1) * (y0 - y1));
    float best = -1.0f;
    int bj = 0;
    #pragma unroll 4
    for (int j = 0; j < MGT; ++j) {
        const float g0 = sgt[j * 5 + 0];
        const float g1 = sgt[j * 5 + 1];
        const float g2 = sgt[j * 5 + 2];
        const float g3 = sgt[j * 5 + 3];
        const float area2 = fabsf((g0 - g2) * (g1 - g3));
        const float xl = fmaxf(x0, g0);
        const float yb = fmaxf(y0, g1);
        const float xr = fminf(x1, g2);
        const float yt = fminf(y1, g3);
        const float inter = fabsf((xl - xr) * (yb - yt));
        float iou = inter / (area1 + area2 - inter);
        if ((xl > xr) || (yb > yt)) iou = 0.0f;
        if (iou > best) { best = iou; bj = j; }  // strict > keeps first max (jnp.argmax)
    }

    // ---- matched_gt with thresholds (compare in double, matching Python floats) ----
    float m0 = sgt[bj * 5 + 0];
    float m1 = sgt[bj * 5 + 1];
    float m2 = sgt[bj * 5 + 2];
    float m3 = sgt[bj * 5 + 3];
    float m4 = sgt[bj * 5 + 4];
    const double q = (double)best;
    if (q <= 0.3) {
        m0 = m1 = m2 = m3 = m4 = -1.0f;
    } else if (q < 0.7) {
        m0 = m1 = m2 = m3 = m4 = NEG_BIG;
    }
    {
        float* mout = out + (size_t)NA * 4 + (size_t)a * 5;
        mout[0] = m0; mout[1] = m1; mout[2] = m2; mout[3] = m3; mout[4] = m4;
    }

    // ---- get_deltas_from_anchors ----
    {
        float4 gd;
        if (m4 < 0.0f) {
            gd.x = gd.y = gd.z = gd.w = NEG_BIG;
        } else {
            const float bx = (m0 + m2) * 0.5f;
            const float by = (m1 + m3) * 0.5f;
            const float bw = fabsf(m0 - m2);
            const float bh = fabsf(m1 - m3);
            gd.x = (bx - px) / pw;
            gd.y = (by - py) / ph;
            gd.z = logf(fmaxf(bw, 1e-12f) / pw);
            gd.w = logf(fmaxf(bh, 1e-12f) / ph);
        }
        *reinterpret_cast<float4*>(out + (size_t)NA * 9 + (size_t)a * 4) = gd;
    }
}

extern "C" void kernel_launch(void* const* d_in, const int* in_sizes, int n_in,
                              void* d_out, int out_size, void* d_ws, size_t ws_size,
                              hipStream_t stream) {
    const float* loc3 = (const float*)d_in[0];
    const float* loc4 = (const float*)d_in[1];
    const float* loc5 = (const float*)d_in[2];
    const float* del3 = (const float*)d_in[3];
    const float* del4 = (const float*)d_in[4];
    const float* del5 = (const float*)d_in[5];
    const float* gt   = (const float*)d_in[6];
    float* out = (float*)d_out;

    const int grid = (NA + 255) / 256;  // 99 blocks
    rpn_fused_kernel<<<grid, 256, 0, stream>>>(loc3, loc4, loc5,
                                               del3, del4, del5, gt, out);
}

// Round 2
// 9.842 us; speedup vs baseline: 1.8755x; 1.8755x over previous
//
#include <hip/hip_runtime.h>
#include <math.h>

#define NP3 19200
#define NP4 4800
#define NP5 1200
#define NA  (NP3 + NP4 + NP5)   // 25200
#define MGT 64

// SCALE_CLAMP = log(224/8) = log(28)
#define SCALE_CLAMP_F 3.3322045101752038f
#define NEG_BIG (-100000000.0f)

// half_w, half_h per (level, aspect_ratio); host-side double math rounded to f32.
__constant__ float c_half[3][3][2] = {
    // p3: area = 1024
    {{22.62741699796952f, 11.313708498984761f},   // ar = 0.5
     {16.0f, 16.0f},                              // ar = 1.0
     {11.313708498984761f, 22.62741699796952f}},  // ar = 2.0
    // p4: area = 4096
    {{45.25483399593904f, 22.62741699796952f},
     {32.0f, 32.0f},
     {22.62741699796952f, 45.25483399593904f}},
    // p5: area = 16384
    {{90.50966799187808f, 45.25483399593904f},
     {64.0f, 64.0f},
     {45.25483399593904f, 90.50966799187808f}},
};

// 4 lanes cooperate per anchor: sub = lane&3 scans GT j in [sub*16, sub*16+16).
// Argmax via exact f64 cross-multiplication of f32 inter/union -> picks a GT whose
// ROUNDED f32 IoU equals the reference's rounded max (rounding is monotone), so the
// final one-shot f32 division reproduces the reference quality bit-exactly.
__global__ __launch_bounds__(256)
void rpn_fused_kernel(const float* __restrict__ loc3,
                      const float* __restrict__ loc4,
                      const float* __restrict__ loc5,
                      const float* __restrict__ del3,
                      const float* __restrict__ del4,
                      const float* __restrict__ del5,
                      const float* __restrict__ gt,     // 64 x 5
                      float* __restrict__ out)
{
    __shared__ float sg0[MGT], sg1[MGT], sg2[MGT], sg3[MGT], sg4[MGT], sa2[MGT];
    const int t = threadIdx.x;
    if (t < MGT) {
        const float g0 = gt[t * 5 + 0];
        const float g1 = gt[t * 5 + 1];
        const float g2 = gt[t * 5 + 2];
        const float g3 = gt[t * 5 + 3];
        const float g4 = gt[t * 5 + 4];
        sg0[t] = g0; sg1[t] = g1; sg2[t] = g2; sg3[t] = g3; sg4[t] = g4;
        sa2[t] = fabsf((g0 - g2) * (g1 - g3));
    }
    __syncthreads();

    const int sub = t & 3;
    const int a = blockIdx.x * 64 + (t >> 2);
    if (a >= NA) return;

    // ---- level decode ----
    int lvl, rel;
    const float* locs;
    const float* dels;
    if (a < NP3)              { lvl = 0; rel = a;              locs = loc3; dels = del3; }
    else if (a < NP3 + NP4)   { lvl = 1; rel = a - NP3;        locs = loc4; dels = del4; }
    else                      { lvl = 2; rel = a - NP3 - NP4;  locs = loc5; dels = del5; }

    const int li = rel / 3;
    const int ar = rel - li * 3;

    // ---- anchor ----
    const float lx = locs[li * 2 + 0];
    const float ly = locs[li * 2 + 1];
    const float hw = c_half[lvl][ar][0];
    const float hh = c_half[lvl][ar][1];
    const float x0 = lx - hw, y0 = ly - hh;
    const float x1 = lx + hw, y1 = ly + hh;

    const float px = (x0 + x1) * 0.5f;
    const float py = (y0 + y1) * 0.5f;
    const float pw = fabsf(x0 - x1);
    const float ph = fabsf(y0 - y1);
    const float area1 = fabsf((x0 - x1) * (y0 - y1));

    // ---- IoU argmax over this lane's 16 GTs (division-free, exact order) ----
    float bi = -1.0f, bu = 1.0f;   // ratio -1 < any iou >= 0, replaced at i=0
    int   bj = sub * 16;
    const int j0 = sub * 16;
    #pragma unroll
    for (int i = 0; i < 16; ++i) {
        const int j = j0 + i;
        const float g0 = sg0[j];
        const float g1 = sg1[j];
        const float g2 = sg2[j];
        const float g3 = sg3[j];
        const float xl = fmaxf(x0, g0);
        const float yb = fmaxf(y0, g1);
        const float xr = fminf(x1, g2);
        const float yt = fminf(y1, g3);
        float inter = fabsf((xl - xr) * (yb - yt));
        if ((xl > xr) || (yb > yt)) inter = 0.0f;
        const float uni = (area1 + sa2[j]) - inter;   // matches ref f32 assoc order
        // exact real-ratio compare: inter/uni > bi/bu  <=>  inter*bu > bi*uni
        const double c1 = (double)bi   * (double)uni;
        const double c2 = (double)inter * (double)bu;
        if (c2 > c1) { bi = inter; bu = uni; bj = j; }   // strict > keeps first max
    }

    // ---- merge across the 4 sub-lanes (smaller index wins exact ties) ----
    #pragma unroll
    for (int m = 1; m <= 2; m <<= 1) {
        const float obi = __shfl_xor(bi, m, 64);
        const float obu = __shfl_xor(bu, m, 64);
        const int   obj = __shfl_xor(bj, m, 64);
        const double c1 = (double)bi  * (double)obu;
        const double c2 = (double)obi * (double)bu;
        if (c2 > c1 || (c2 == c1 && obj < bj)) { bi = obi; bu = obu; bj = obj; }
    }

    // ---- quality + classification (double thresholds, matching Python floats) ----
    const float q = bi / bu;     // one exact IEEE f32 division
    float m0 = sg0[bj], m1 = sg1[bj], m2 = sg2[bj], m3 = sg3[bj], m4 = sg4[bj];
    const double qd = (double)q;
    if (qd <= 0.3) {
        m0 = m1 = m2 = m3 = m4 = -1.0f;
    } else if (qd < 0.7) {
        m0 = m1 = m2 = m3 = m4 = NEG_BIG;
    }

    // ---- outputs, split across sub-lanes ----
    if (sub == 0) {
        // proposals = apply_deltas
        const float tx = dels[rel * 4 + 0];
        const float ty = dels[rel * 4 + 1];
        const float tw = fminf(dels[rel * 4 + 2], SCALE_CLAMP_F);
        const float th = fminf(dels[rel * 4 + 3], SCALE_CLAMP_F);
        const float bx = px + pw * tx;
        const float by = py + ph * ty;
        const float bw = pw * expf(tw);
        const float bh = ph * expf(th);
        float4 prop;
        prop.x = bx - bw * 0.5f;
        prop.y = by - bh * 0.5f;
        prop.z = bx + bw * 0.5f;
        prop.w = by + bw * 0.5f;   // reference uses bw here (ref bug, replicated)
        *reinterpret_cast<float4*>(out + (size_t)a * 4) = prop;
    } else if (sub == 1) {
        float* mout = out + (size_t)NA * 4 + (size_t)a * 5;
        mout[0] = m0; mout[1] = m1; mout[2] = m2; mout[3] = m3; mout[4] = m4;
    } else if (sub == 2) {
        float4 gd;
        if (m4 < 0.0f) {
            gd.x = gd.y = gd.z = gd.w = NEG_BIG;
        } else {
            const float bx = (m0 + m2) * 0.5f;
            const float by = (m1 + m3) * 0.5f;
            const float bw = fabsf(m0 - m2);
            const float bh = fabsf(m1 - m3);
            gd.x = (bx - px) / pw;
            gd.y = (by - py) / ph;
            gd.z = logf(fmaxf(bw, 1e-12f) / pw);
            gd.w = logf(fmaxf(bh, 1e-12f) / ph);
        }
        *reinterpret_cast<float4*>(out + (size_t)NA * 9 + (size_t)a * 4) = gd;
    }
}

extern "C" void kernel_launch(void* const* d_in, const int* in_sizes, int n_in,
                              void* d_out, int out_size, void* d_ws, size_t ws_size,
                              hipStream_t stream) {
    const float* loc3 = (const float*)d_in[0];
    const float* loc4 = (const float*)d_in[1];
    const float* loc5 = (const float*)d_in[2];
    const float* del3 = (const float*)d_in[3];
    const float* del4 = (const float*)d_in[4];
    const float* del5 = (const float*)d_in[5];
    const float* gt   = (const float*)d_in[6];
    float* out = (float*)d_out;

    const int grid = (NA + 63) / 64;   // 394 blocks, 64 anchors each, 4 lanes/anchor
    rpn_fused_kernel<<<grid, 256, 0, stream>>>(loc3, loc4, loc5,
                                               del3, del4, del5, gt, out);
}